// Round 1
// baseline (727.338 us; speedup 1.0000x reference)
//
#include <hip/hip_runtime.h>
#include <math.h>
#include <float.h>
#include <limits.h>

#define N 8192
#define D 64
#define TOPK 32

// ---------------------------------------------------------------------------
// Kernel 1: row norms of X1 and X2 -> ws[0..2N)
// ---------------------------------------------------------------------------
__global__ __launch_bounds__(256) void norms_kernel(
    const float* __restrict__ X1, const float* __restrict__ X2,
    float* __restrict__ nrm)
{
    int id = blockIdx.x * blockDim.x + threadIdx.x;
    if (id >= 2 * N) return;
    const float* X = (id < N) ? X1 : X2;
    int r = (id < N) ? id : id - N;
    const float4* p = (const float4*)(X + (size_t)r * D);
    float s = 0.f;
#pragma unroll
    for (int q = 0; q < D / 4; ++q) {
        float4 v = p[q];
        s += v.x * v.x + v.y * v.y + v.z * v.z + v.w * v.w;
    }
    nrm[id] = s;
}

// ---------------------------------------------------------------------------
// Kernel 2: neg_dist[i][j] = -sqrt(max(n1[i]+n2[j]-2*dot, 0)) -> out (dense)
// 64x64 tile per 256-thread block, K=64 fully staged in LDS (transposed).
// LDA=68: keeps ds_read_b128 16B-aligned, staging writes at 2-way alias (free).
// ---------------------------------------------------------------------------
#define BM 64
#define BN 64
#define LDA 68

__global__ __launch_bounds__(256) void dist_kernel(
    const float* __restrict__ X1, const float* __restrict__ X2,
    const float* __restrict__ nrm, float* __restrict__ out)
{
    __shared__ float As[D * LDA];   // As[d][r] = X1[row0+r][d]
    __shared__ float Bs[D * LDA];   // Bs[d][c] = X2[col0+c][d]

    const int t = threadIdx.x;
    const int row0 = blockIdx.y * BM;
    const int col0 = blockIdx.x * BN;

    // stage both tiles, transposed
#pragma unroll
    for (int p = 0; p < 4; ++p) {
        int lin = p * 256 + t;          // 0..1023
        int r   = lin >> 4;             // 0..63
        int d4  = (lin & 15) << 2;      // 0,4,...,60
        float4 a = *(const float4*)(X1 + (size_t)(row0 + r) * D + d4);
        As[(d4 + 0) * LDA + r] = a.x;
        As[(d4 + 1) * LDA + r] = a.y;
        As[(d4 + 2) * LDA + r] = a.z;
        As[(d4 + 3) * LDA + r] = a.w;
        float4 b = *(const float4*)(X2 + (size_t)(col0 + r) * D + d4);
        Bs[(d4 + 0) * LDA + r] = b.x;
        Bs[(d4 + 1) * LDA + r] = b.y;
        Bs[(d4 + 2) * LDA + r] = b.z;
        Bs[(d4 + 3) * LDA + r] = b.w;
    }
    __syncthreads();

    const int tx = t & 15;   // col group
    const int ty = t >> 4;   // row group
    float acc[4][4] = {};

#pragma unroll 16
    for (int k = 0; k < D; ++k) {
        float4 a = *(const float4*)&As[k * LDA + 4 * ty];
        float4 b = *(const float4*)&Bs[k * LDA + 4 * tx];
        acc[0][0] += a.x * b.x; acc[0][1] += a.x * b.y; acc[0][2] += a.x * b.z; acc[0][3] += a.x * b.w;
        acc[1][0] += a.y * b.x; acc[1][1] += a.y * b.y; acc[1][2] += a.y * b.z; acc[1][3] += a.y * b.w;
        acc[2][0] += a.z * b.x; acc[2][1] += a.z * b.y; acc[2][2] += a.z * b.z; acc[2][3] += a.z * b.w;
        acc[3][0] += a.w * b.x; acc[3][1] += a.w * b.y; acc[3][2] += a.w * b.z; acc[3][3] += a.w * b.w;
    }

    float na[4], nb[4];
#pragma unroll
    for (int i = 0; i < 4; ++i) na[i] = nrm[row0 + 4 * ty + i];
#pragma unroll
    for (int j = 0; j < 4; ++j) nb[j] = nrm[N + col0 + 4 * tx + j];

#pragma unroll
    for (int i = 0; i < 4; ++i) {
        float4 o;
        float* po = (float*)&o;
#pragma unroll
        for (int j = 0; j < 4; ++j) {
            float sq = na[i] + nb[j] - 2.0f * acc[i][j];
            po[j] = -sqrtf(fmaxf(sq, 0.0f));
        }
        *(float4*)(out + (size_t)(row0 + 4 * ty + i) * N + col0 + 4 * tx) = o;
    }
}

// ---------------------------------------------------------------------------
// Kernel 3: per-row top-32 -> softmax -> zero row + scatter; write score.
// One 256-thread block per row.
// ---------------------------------------------------------------------------
#define NB 256
#define CAP 1024

__global__ __launch_bounds__(256) void topk_kernel(
    float* __restrict__ out, float* __restrict__ score_out)
{
    const int r = blockIdx.x;
    const int t = threadIdx.x;
    float* row = out + (size_t)r * N;

    // load 32 values per thread (coalesced float4)
    float v[32];
#pragma unroll
    for (int c = 0; c < 8; ++c) {
        float4 x = ((const float4*)row)[c * 256 + t];
        v[4 * c + 0] = x.x; v[4 * c + 1] = x.y;
        v[4 * c + 2] = x.z; v[4 * c + 3] = x.w;
    }
    // value v[u] corresponds to column j = 4*((u>>2)*256 + t) + (u&3)

    // ---- block max ----
    float m = v[0];
#pragma unroll
    for (int u = 1; u < 32; ++u) m = fmaxf(m, v[u]);
    for (int off = 32; off > 0; off >>= 1) m = fmaxf(m, __shfl_down(m, off));
    __shared__ float smax[4];
    if ((t & 63) == 0) smax[t >> 6] = m;
    __syncthreads();
    const float M = fmaxf(fmaxf(smax[0], smax[1]), fmaxf(smax[2], smax[3]));

    // ---- histogram threshold selection ----
    __shared__ int hist[NB];
    __shared__ int scan[NB];
    __shared__ int bstar_s;
    __shared__ int cnt;
    __shared__ float cand_v[CAP];
    __shared__ int   cand_j[CAP];

    float binscale = 0.f;
    int bstar = -1;
    for (int attempt = 0; attempt < 2 && bstar < 0; ++attempt) {
        const float W = (attempt == 0) ? 4.0f : 33.0f;  // W=33 always covers
        binscale = (float)NB / W;
        hist[t] = 0;
        __syncthreads();
#pragma unroll
        for (int u = 0; u < 32; ++u) {
            int b = (int)((M - v[u]) * binscale);
            if (b < NB) atomicAdd(&hist[b], 1);
        }
        __syncthreads();
        // inclusive prefix scan over bins (best bin = 0)
        int val = hist[t];
        scan[t] = val;
        __syncthreads();
        for (int off = 1; off < NB; off <<= 1) {
            int y = (t >= off) ? scan[t - off] : 0;
            __syncthreads();
            val += y;
            scan[t] = val;
            __syncthreads();
        }
        if (t == 0) bstar_s = -1;
        __syncthreads();
        if (scan[t] >= TOPK && (t == 0 || scan[t - 1] < TOPK)) bstar_s = t;
        __syncthreads();
        bstar = bstar_s;   // uniform
    }
    if (bstar < 0) bstar = NB - 1;  // unreachable safety

    // ---- compact candidates (same binning formula -> exact consistency) ----
    if (t == 0) cnt = 0;
    __syncthreads();
#pragma unroll
    for (int u = 0; u < 32; ++u) {
        int b = (int)((M - v[u]) * binscale);
        if (b <= bstar) {
            int p = atomicAdd(&cnt, 1);
            if (p < CAP) {
                cand_v[p] = v[u];
                cand_j[p] = 4 * ((u >> 2) * 256 + t) + (u & 3);
            }
        }
    }
    __syncthreads();
    const int C = (cnt < CAP) ? cnt : CAP;   // C >= 32 guaranteed

    // ---- 32 x iterative argmax (tie-break: larger v, then smaller j) ----
    __shared__ float sel_v[TOPK];
    __shared__ int   sel_j[TOPK];
    __shared__ float wv[4]; __shared__ int wj[4], wp[4];

    for (int it = 0; it < TOPK; ++it) {
        float bv = -FLT_MAX; int bj = INT_MAX; int bp = -1;
        for (int p = t; p < C; p += 256) {
            float cv = cand_v[p]; int cj = cand_j[p];
            if (cv > bv || (cv == bv && cj < bj)) { bv = cv; bj = cj; bp = p; }
        }
        for (int off = 32; off > 0; off >>= 1) {
            float ov = __shfl_down(bv, off);
            int   oj = __shfl_down(bj, off);
            int   op = __shfl_down(bp, off);
            if (ov > bv || (ov == bv && oj < bj)) { bv = ov; bj = oj; bp = op; }
        }
        if ((t & 63) == 0) { wv[t >> 6] = bv; wj[t >> 6] = bj; wp[t >> 6] = bp; }
        __syncthreads();
        if (t == 0) {
            float fv = wv[0]; int fj = wj[0]; int fp = wp[0];
            for (int w = 1; w < 4; ++w) {
                if (wv[w] > fv || (wv[w] == fv && wj[w] < fj)) {
                    fv = wv[w]; fj = wj[w]; fp = wp[w];
                }
            }
            sel_v[it] = fv; sel_j[it] = fj;
            cand_v[fp] = -FLT_MAX;   // remove winner
        }
        __syncthreads();
    }

    // ---- softmax over the 32 selected (sel_v is descending; sel_v[0]=max) ----
    __shared__ float ex[TOPK];
    __shared__ float Zs;
    if (t < TOPK) ex[t] = expf(sel_v[t] - sel_v[0]);
    __syncthreads();
    if (t == 0) {
        float Z = 0.f;
        for (int i = 0; i < TOPK; ++i) Z += ex[i];
        Zs = Z;
    }
    __syncthreads();
    if (t < TOPK) score_out[(size_t)r * TOPK + t] = ex[t] / Zs;

    // ---- zero the row, then scatter the 32 scores ----
    __syncthreads();
    const float4 z = make_float4(0.f, 0.f, 0.f, 0.f);
#pragma unroll
    for (int c = 0; c < 8; ++c) ((float4*)row)[c * 256 + t] = z;
    __syncthreads();
    if (t < TOPK) row[sel_j[t]] = ex[t] / Zs;
}

// ---------------------------------------------------------------------------
extern "C" void kernel_launch(void* const* d_in, const int* in_sizes, int n_in,
                              void* d_out, int out_size, void* d_ws, size_t ws_size,
                              hipStream_t stream)
{
    const float* X1 = (const float*)d_in[0];
    const float* X2 = (const float*)d_in[1];
    float* out = (float*)d_out;
    float* nrm = (float*)d_ws;                 // 2*N floats = 64 KB

    norms_kernel<<<(2 * N + 255) / 256, 256, 0, stream>>>(X1, X2, nrm);

    dim3 grid(N / BN, N / BM);
    dist_kernel<<<grid, 256, 0, stream>>>(X1, X2, nrm, out);

    topk_kernel<<<N, 256, 0, stream>>>(out, out + (size_t)N * N);
}